// Round 6
// baseline (237.893 us; speedup 1.0000x reference)
//
#include <hip/hip_runtime.h>

typedef __bf16 bhalf;
typedef __bf16 bhalf8 __attribute__((ext_vector_type(8)));
typedef __bf16 bhalf4 __attribute__((ext_vector_type(4)));
typedef float f32x4 __attribute__((ext_vector_type(4)));

typedef __attribute__((address_space(1))) const void* gas_p;
typedef __attribute__((address_space(3))) void* las_p;

#define T_SEQ 2048
#define HIDN  2048
#define NQH   32
#define NKVH  8
#define DH    64
#define NQKV  3072

// ---------------- elementwise cast fp32 -> bf16 ----------------
__global__ __launch_bounds__(256) void cast_bf16_k(const float* __restrict__ in,
                                                   bhalf* __restrict__ out, int n) {
  int i = (blockIdx.x * 256 + threadIdx.x) * 4;
  if (i + 3 < n) {
    float4 v = *(const float4*)(in + i);
    bhalf4 o;
    o[0] = (bhalf)v.x; o[1] = (bhalf)v.y; o[2] = (bhalf)v.z; o[3] = (bhalf)v.w;
    *(bhalf4*)(out + i) = o;
  }
}

// ------------- transpose + cast fp32->bf16, 64x64 tile: out[C][R] = bf16(in[R][C]) ----
__global__ __launch_bounds__(256) void transpose_cast64_k(const float* __restrict__ in,
                                                          bhalf* __restrict__ out,
                                                          int R, int C) {
  __shared__ bhalf tile[64][72];
  int tid = threadIdx.x;
  int bx = blockIdx.x * 64;
  int by = blockIdx.y * 64;
  int rl = tid >> 4, c4 = (tid & 15) * 4;
#pragma unroll
  for (int p = 0; p < 4; ++p) {
    float4 v = *(const float4*)(in + (size_t)(by + rl + 16 * p) * C + bx + c4);
    bhalf4 b;
    b[0] = (bhalf)v.x; b[1] = (bhalf)v.y; b[2] = (bhalf)v.z; b[3] = (bhalf)v.w;
    *(bhalf4*)&tile[rl + 16 * p][c4] = b;
  }
  __syncthreads();
  int c = tid >> 2, r0 = (tid & 3) * 16;
  bhalf8 o0, o1;
#pragma unroll
  for (int j = 0; j < 8; ++j) { o0[j] = tile[r0 + j][c]; o1[j] = tile[r0 + 8 + j][c]; }
  *(bhalf8*)(out + (size_t)(bx + c) * R + by + r0) = o0;
  *(bhalf8*)(out + (size_t)(bx + c) * R + by + r0 + 8) = o1;
}

// ---------------- shared GEMM core: 64(M) x 64(N) tile, BK=64, 4 M-stacked waves ------
// wave wv owns rows wv*16..wv*16+15; acc[ni(4)] of 16x16x32 bf16 MFMAs.
// XOR-swizzled LDS staged via global_load_lds width=16.
__device__ __forceinline__ void gemm_core64(const bhalf* __restrict__ A,
                                            const bhalf* __restrict__ Bt,
                                            int Kstride, int Klen,
                                            int bm, int bn, int tid,
                                            bhalf* As, bhalf* Bs, f32x4 acc[4]) {
  int lane = tid & 63, wv = tid >> 6;
  int m16 = lane & 15, q4 = lane >> 4;
  int srow = tid >> 3;                       // 0..31
  int scol = ((tid & 7) ^ (srow & 7)) * 8;   // XOR-swizzled source col block
  const bhalf* asrc = A + (size_t)(bm + srow) * Kstride + scol;
  const bhalf* bsrc = Bt + (size_t)(bn + srow) * Kstride + scol;
  bhalf* adst = As + (wv * 8) * 64;
  bhalf* bdst = Bs + (wv * 8) * 64;
  int swz = m16 & 7;

  for (int k0 = 0; k0 < Klen; k0 += 64) {
#pragma unroll
    for (int c = 0; c < 2; ++c) {
      __builtin_amdgcn_global_load_lds((gas_p)(asrc + (size_t)(c * 32) * Kstride + k0),
                                       (las_p)(adst + c * 2048), 16, 0, 0);
      __builtin_amdgcn_global_load_lds((gas_p)(bsrc + (size_t)(c * 32) * Kstride + k0),
                                       (las_p)(bdst + c * 2048), 16, 0, 0);
    }
    __syncthreads();
    bhalf8 af[2], bf[4][2];
#pragma unroll
    for (int ks = 0; ks < 2; ++ks)
      af[ks] = *(const bhalf8*)&As[(wv * 16 + m16) * 64 + (((ks * 4 + q4) ^ swz) * 8)];
#pragma unroll
    for (int ni = 0; ni < 4; ++ni)
#pragma unroll
      for (int ks = 0; ks < 2; ++ks)
        bf[ni][ks] = *(const bhalf8*)&Bs[(ni * 16 + m16) * 64 + (((ks * 4 + q4) ^ swz) * 8)];
#pragma unroll
    for (int ni = 0; ni < 4; ++ni) {
      acc[ni] = __builtin_amdgcn_mfma_f32_16x16x32_bf16(af[0], bf[ni][0], acc[ni], 0, 0, 0);
      acc[ni] = __builtin_amdgcn_mfma_f32_16x16x32_bf16(af[1], bf[ni][1], acc[ni], 0, 0, 0);
    }
    __syncthreads();
  }
}

// ---------------- GEMM1 + fused RMSNorm + RoPE + split + cast (+ direct V^T) ---------
// 64x64 tile; N-tile == one head (h = blockIdx.x: 0..31 q, 32..39 k, 40..47 v).
__global__ __launch_bounds__(256) void gemm1_fused_k(const bhalf* __restrict__ A,
                                                     const bhalf* __restrict__ Bt,
                                                     const int* __restrict__ pos,
                                                     const float* __restrict__ qw,
                                                     const float* __restrict__ kw,
                                                     bhalf* __restrict__ qo,
                                                     bhalf* __restrict__ ko,
                                                     bhalf* __restrict__ vt) {
  __shared__ __align__(16) bhalf As[64 * 64];
  __shared__ __align__(16) bhalf Bs[64 * 64];
  int tid = threadIdx.x, lane = tid & 63, wv = tid >> 6;
  int m16 = lane & 15, q4 = lane >> 4;
  int bm = blockIdx.y * 64, bn = blockIdx.x * 64, h = blockIdx.x;
  f32x4 zero4 = {0.f, 0.f, 0.f, 0.f};
  f32x4 acc[4];
#pragma unroll
  for (int ni = 0; ni < 4; ++ni) acc[ni] = zero4;

  gemm_core64(A, Bt, HIDN, HIDN, bm, bn, tid, As, Bs, acc);

  if (h < 40) {
    float wd[4];
    const float* wptr = (h < 32) ? qw : kw;
#pragma unroll
    for (int ni = 0; ni < 4; ++ni) wd[ni] = wptr[ni * 16 + m16];
    float f0 = exp2f((float)m16 * -0.6228615177913804f);
    float f1 = f0 * 0.001f;  // theta^(-16/32) = 1e-3
#pragma unroll
    for (int r = 0; r < 4; ++r) {
      int trow = bm + wv * 16 + q4 * 4 + r;
      float x0 = acc[0][r], x1 = acc[1][r], x2 = acc[2][r], x3 = acc[3][r];
      float ss = x0 * x0 + x1 * x1 + x2 * x2 + x3 * x3;
      ss += __shfl_xor(ss, 1);
      ss += __shfl_xor(ss, 2);
      ss += __shfl_xor(ss, 4);
      ss += __shfl_xor(ss, 8);
      float sc = rsqrtf(ss * (1.0f / 64.0f) + 1e-5f);
      float y0 = x0 * sc * wd[0], y1 = x1 * sc * wd[1];
      float y2 = x2 * sc * wd[2], y3 = x3 * sc * wd[3];
      float p = (float)pos[trow];
      float a0 = p * f0, a1 = p * f1;
      float c0 = cosf(a0), s0 = sinf(a0), c1 = cosf(a1), s1 = sinf(a1);
      float o0 = y0 * c0 - y2 * s0, o2 = y2 * c0 + y0 * s0;
      float o1 = y1 * c1 - y3 * s1, o3 = y3 * c1 + y1 * s1;
      bhalf* dst = (h < 32) ? (qo + (size_t)trow * 2048 + h * 64 + m16)
                            : (ko + (size_t)trow * 512 + (h - 32) * 64 + m16);
      dst[0] = (bhalf)o0; dst[16] = (bhalf)o1; dst[32] = (bhalf)o2; dst[48] = (bhalf)o3;
    }
  } else {
    // V: write transposed directly — vt[(h-40)*64 + d][trow]
#pragma unroll
    for (int r = 0; r < 4; ++r) {
      int trow = bm + wv * 16 + q4 * 4 + r;
#pragma unroll
      for (int ni = 0; ni < 4; ++ni)
        vt[(size_t)((h - 40) * 64 + ni * 16 + m16) * 2048 + trow] = (bhalf)acc[ni][r];
    }
  }
}

// ---------------- GEMM2 (64x64 tile, split-K=2): partial fp32 out ----------------
__global__ __launch_bounds__(256) void gemm2_k(const bhalf* __restrict__ A,
                                               const bhalf* __restrict__ Bt,
                                               float* __restrict__ Cpart) {
  __shared__ __align__(16) bhalf As[64 * 64];
  __shared__ __align__(16) bhalf Bs[64 * 64];
  int tid = threadIdx.x, lane = tid & 63, wv = tid >> 6;
  int m16 = lane & 15, q4 = lane >> 4;
  int bm = blockIdx.y * 64, bn = blockIdx.x * 64;
  int slice = blockIdx.z;
  f32x4 zero4 = {0.f, 0.f, 0.f, 0.f};
  f32x4 acc[4];
#pragma unroll
  for (int ni = 0; ni < 4; ++ni) acc[ni] = zero4;

  gemm_core64(A + slice * 1024, Bt + slice * 1024, HIDN, 1024, bm, bn, tid, As, Bs, acc);

  float* C = Cpart + (size_t)slice * (T_SEQ * HIDN);
#pragma unroll
  for (int r = 0; r < 4; ++r) {
    size_t base = (size_t)(bm + wv * 16 + q4 * 4 + r) * 2048 + bn + m16;
    C[base] = acc[0][r]; C[base + 16] = acc[1][r];
    C[base + 32] = acc[2][r]; C[base + 48] = acc[3][r];
  }
}

// ---------------- split-K reduce: out = p0 + p1 ----------------
__global__ __launch_bounds__(256) void add2_k(const float* __restrict__ p0,
                                              const float* __restrict__ p1,
                                              float* __restrict__ out) {
  int i = (blockIdx.x * 256 + threadIdx.x) * 4;
  float4 a = *(const float4*)(p0 + i);
  float4 b = *(const float4*)(p1 + i);
  float4 o = {a.x + b.x, a.y + b.y, a.z + b.z, a.w + b.w};
  *(float4*)(out + i) = o;
}

// ---------------- flash attention (causal GQA), fixed-max softmax ----------------
// (R4 version — verified best.) grid (NQH, 32): block = (head, 64 q-rows),
// qt = 31 - by (heavy first). 4 waves; wave owns 16 q-rows. s-chunk 64, K/V^T
// double-buffered via global_load_lds + XOR swizzle, 1 barrier/chunk. Interior
// chunks take an unmasked fast path; only the diagonal chunk (c==qt) masks.
__global__ __launch_bounds__(256) void attn_k(const bhalf* __restrict__ q,
                                              const bhalf* __restrict__ k,
                                              const bhalf* __restrict__ vt,
                                              bhalf* __restrict__ o) {
  __shared__ __align__(16) bhalf Kb[2][4096];
  __shared__ __align__(16) bhalf Vb[2][4096];
  __shared__ __align__(16) bhalf Pb[4][16][72];
  int tid = threadIdx.x, lane = tid & 63, w = tid >> 6;
  int h = blockIdx.x, kh = h >> 2;
  int qt = 31 - blockIdx.y;
  int qb = qt * 64;
  int m16 = lane & 15, q4 = lane >> 4;
  int wrow0 = qb + w * 16;

  const float C1 = 0.18033688011112042f;  // 0.125 * log2(e)
  const float C2 = 11.541560327111707f;   // 8 * log2(e)

  const bhalf* qp = q + (size_t)(wrow0 + m16) * 2048 + h * 64;
  bhalf8 qf0 = *(const bhalf8*)(qp + q4 * 8);
  bhalf8 qf1 = *(const bhalf8*)(qp + 32 + q4 * 8);

  int srow = tid >> 3;
  int scol = ((tid & 7) ^ (srow & 7)) * 8;
  const bhalf* ksrc = k + (size_t)srow * 512 + kh * 64 + scol;
  const bhalf* vsrc = vt + (size_t)(kh * 64 + srow) * 2048 + scol;
  bhalf* kdst = &Kb[0][0] + w * 512;
  bhalf* vdst = &Vb[0][0] + w * 512;

  auto stage = [&](int c) {
    int buf = c & 1, s0 = c * 64;
#pragma unroll
    for (int j = 0; j < 2; ++j) {
      __builtin_amdgcn_global_load_lds((gas_p)(ksrc + (size_t)(s0 + j * 32) * 512),
                                       (las_p)(kdst + buf * 4096 + j * 2048), 16, 0, 0);
      __builtin_amdgcn_global_load_lds((gas_p)(vsrc + (size_t)(j * 32) * 2048 + s0),
                                       (las_p)(vdst + buf * 4096 + j * 2048), 16, 0, 0);
    }
  };

  f32x4 zero4 = {0.f, 0.f, 0.f, 0.f};
  f32x4 oac[4];
  float psum[4] = {0.f, 0.f, 0.f, 0.f};
#pragma unroll
  for (int ni = 0; ni < 4; ++ni) oac[ni] = zero4;
  int swz = m16 & 7;

  stage(0);
  for (int c = 0; c <= qt; ++c) {
    __syncthreads();  // implicit vmcnt(0) drain: buf c ready, prior buf reads done
    if (c < qt) stage(c + 1);
    int buf = c & 1, s0 = c * 64;
    if (c < qt) {
      bhalf8 kf[4][2];
#pragma unroll
      for (int st = 0; st < 4; ++st)
#pragma unroll
        for (int ks = 0; ks < 2; ++ks)
          kf[st][ks] = *(const bhalf8*)&Kb[buf][(st * 16 + m16) * 64 + (((ks * 4 + q4) ^ swz) * 8)];
      f32x4 sv[4];
#pragma unroll
      for (int st = 0; st < 4; ++st) {
        f32x4 t0 = __builtin_amdgcn_mfma_f32_16x16x32_bf16(qf0, kf[st][0], zero4, 0, 0, 0);
        sv[st] = __builtin_amdgcn_mfma_f32_16x16x32_bf16(qf1, kf[st][1], t0, 0, 0, 0);
      }
#pragma unroll
      for (int st = 0; st < 4; ++st)
#pragma unroll
        for (int r = 0; r < 4; ++r) {
          float pe = exp2f(sv[st][r] * C1 - C2);
          psum[r] += pe;
          Pb[w][q4 * 4 + r][st * 16 + m16] = (bhalf)pe;
        }
      bhalf8 vf[4][2];
#pragma unroll
      for (int ni = 0; ni < 4; ++ni)
#pragma unroll
        for (int ks = 0; ks < 2; ++ks)
          vf[ni][ks] = *(const bhalf8*)&Vb[buf][(ni * 16 + m16) * 64 + (((ks * 4 + q4) ^ swz) * 8)];
      bhalf8 ap0 = *(const bhalf8*)&Pb[w][m16][q4 * 8];
      bhalf8 ap1 = *(const bhalf8*)&Pb[w][m16][32 + q4 * 8];
#pragma unroll
      for (int ni = 0; ni < 4; ++ni) {
        oac[ni] = __builtin_amdgcn_mfma_f32_16x16x32_bf16(ap0, vf[ni][0], oac[ni], 0, 0, 0);
        oac[ni] = __builtin_amdgcn_mfma_f32_16x16x32_bf16(ap1, vf[ni][1], oac[ni], 0, 0, 0);
      }
    } else {
      bhalf8 kf[4][2];
      f32x4 sv[4];
#pragma unroll
      for (int st = 0; st < 4; ++st)
        if (st <= w) {
#pragma unroll
          for (int ks = 0; ks < 2; ++ks)
            kf[st][ks] = *(const bhalf8*)&Kb[buf][(st * 16 + m16) * 64 + (((ks * 4 + q4) ^ swz) * 8)];
          f32x4 t0 = __builtin_amdgcn_mfma_f32_16x16x32_bf16(qf0, kf[st][0], zero4, 0, 0, 0);
          sv[st] = __builtin_amdgcn_mfma_f32_16x16x32_bf16(qf1, kf[st][1], t0, 0, 0, 0);
        }
      int stwr = (w >= 2) ? 3 : 1;
#pragma unroll
      for (int st = 0; st < 4; ++st) {
        if (st > stwr) continue;
#pragma unroll
        for (int r = 0; r < 4; ++r) {
          float pe = 0.f;
          if (st <= w) {
            int trow = wrow0 + q4 * 4 + r;
            int col = s0 + st * 16 + m16;
            pe = (col <= trow) ? exp2f(sv[st][r] * C1 - C2) : 0.f;
          }
          psum[r] += pe;
          Pb[w][q4 * 4 + r][st * 16 + m16] = (bhalf)pe;
        }
      }
      int ksmax = (w >= 2) ? 1 : 0;
      bhalf8 vf[4][2];
#pragma unroll
      for (int ni = 0; ni < 4; ++ni)
#pragma unroll
        for (int ks = 0; ks < 2; ++ks)
          if (ks <= ksmax)
            vf[ni][ks] = *(const bhalf8*)&Vb[buf][(ni * 16 + m16) * 64 + (((ks * 4 + q4) ^ swz) * 8)];
      bhalf8 ap0 = *(const bhalf8*)&Pb[w][m16][q4 * 8];
#pragma unroll
      for (int ni = 0; ni < 4; ++ni)
        oac[ni] = __builtin_amdgcn_mfma_f32_16x16x32_bf16(ap0, vf[ni][0], oac[ni], 0, 0, 0);
      if (ksmax) {
        bhalf8 ap1 = *(const bhalf8*)&Pb[w][m16][32 + q4 * 8];
#pragma unroll
        for (int ni = 0; ni < 4; ++ni)
          oac[ni] = __builtin_amdgcn_mfma_f32_16x16x32_bf16(ap1, vf[ni][1], oac[ni], 0, 0, 0);
      }
    }
  }
#pragma unroll
  for (int r = 0; r < 4; ++r) {
    float ps = psum[r];
    ps += __shfl_xor(ps, 1);
    ps += __shfl_xor(ps, 2);
    ps += __shfl_xor(ps, 4);
    ps += __shfl_xor(ps, 8);
    psum[r] = 1.0f / ps;
  }
#pragma unroll
  for (int ni = 0; ni < 4; ++ni)
#pragma unroll
    for (int r = 0; r < 4; ++r) {
      int trow = wrow0 + q4 * 4 + r;
      o[(size_t)trow * 2048 + h * 64 + ni * 16 + m16] = (bhalf)(oac[ni][r] * psum[r]);
    }
}

extern "C" void kernel_launch(void* const* d_in, const int* in_sizes, int n_in,
                              void* d_out, int out_size, void* d_ws, size_t ws_size,
                              hipStream_t stream) {
  const int* positions = (const int*)d_in[0];
  const float* hidden  = (const float*)d_in[1];
  const float* w_qkv   = (const float*)d_in[2];
  const float* w_out   = (const float*)d_in[3];
  const float* q_ln    = (const float*)d_in[4];
  const float* k_ln    = (const float*)d_in[5];
  float* out = (float*)d_out;

  char* wsp = (char*)d_ws;
  bhalf* woutT   = (bhalf*)(wsp);                 //  0 .. 8.39 MB
  bhalf* attn_bf = (bhalf*)(wsp + 8388608);       //  8.39 .. 16.78
  float* part0   = (float*)(wsp + 16777216);      // 16.78 .. 33.55 (overlays hid/wqkvT)
  float* part1   = (float*)(wsp + 33554432);      // 33.55 .. 50.33
  bhalf* hid_bf  = (bhalf*)(wsp + 16777216);      // dead after gemm1
  bhalf* wqkvT   = (bhalf*)(wsp + 25165824);      // dead after gemm1
  bhalf* q_bf    = (bhalf*)(wsp + 50331648);      // 50.33 .. 58.72
  bhalf* k_bf    = (bhalf*)(wsp + 58720256);      // 58.72 .. 60.82
  bhalf* vt_g    = (bhalf*)(wsp + 60817408);      // 60.82 .. 62.91

  cast_bf16_k<<<T_SEQ * HIDN / 1024, 256, 0, stream>>>(hidden, hid_bf, T_SEQ * HIDN);
  transpose_cast64_k<<<dim3(NQKV / 64, HIDN / 64), 256, 0, stream>>>(w_qkv, wqkvT, HIDN, NQKV);
  transpose_cast64_k<<<dim3(HIDN / 64, HIDN / 64), 256, 0, stream>>>(w_out, woutT, HIDN, HIDN);
  gemm1_fused_k<<<dim3(NQKV / 64, T_SEQ / 64), 256, 0, stream>>>(
      hid_bf, wqkvT, positions, q_ln, k_ln, q_bf, k_bf, vt_g);
  attn_k<<<dim3(NQH, 32), 256, 0, stream>>>(q_bf, k_bf, vt_g, attn_bf);
  gemm2_k<<<dim3(HIDN / 64, T_SEQ / 64, 2), 256, 0, stream>>>(attn_bf, woutT, part0);
  add2_k<<<T_SEQ * HIDN / 1024, 256, 0, stream>>>(part0, part1, out);
}

// Round 7
// 233.041 us; speedup vs baseline: 1.0208x; 1.0208x over previous
//
#include <hip/hip_runtime.h>

typedef __bf16 bhalf;
typedef __bf16 bhalf8 __attribute__((ext_vector_type(8)));
typedef __bf16 bhalf4 __attribute__((ext_vector_type(4)));
typedef float f32x4 __attribute__((ext_vector_type(4)));

typedef __attribute__((address_space(1))) const void* gas_p;
typedef __attribute__((address_space(3))) void* las_p;

#define T_SEQ 2048
#define HIDN  2048
#define NQH   32
#define NKVH  8
#define DH    64
#define NQKV  3072

// ---------------- elementwise cast fp32 -> bf16 ----------------
__global__ __launch_bounds__(256) void cast_bf16_k(const float* __restrict__ in,
                                                   bhalf* __restrict__ out, int n) {
  int i = (blockIdx.x * 256 + threadIdx.x) * 4;
  if (i + 3 < n) {
    float4 v = *(const float4*)(in + i);
    bhalf4 o;
    o[0] = (bhalf)v.x; o[1] = (bhalf)v.y; o[2] = (bhalf)v.z; o[3] = (bhalf)v.w;
    *(bhalf4*)(out + i) = o;
  }
}

// ------------- transpose + cast fp32->bf16, 64x64 tile: out[C][R] = bf16(in[R][C]) ----
__global__ __launch_bounds__(256) void transpose_cast64_k(const float* __restrict__ in,
                                                          bhalf* __restrict__ out,
                                                          int R, int C) {
  __shared__ bhalf tile[64][72];
  int tid = threadIdx.x;
  int bx = blockIdx.x * 64;
  int by = blockIdx.y * 64;
  int rl = tid >> 4, c4 = (tid & 15) * 4;
#pragma unroll
  for (int p = 0; p < 4; ++p) {
    float4 v = *(const float4*)(in + (size_t)(by + rl + 16 * p) * C + bx + c4);
    bhalf4 b;
    b[0] = (bhalf)v.x; b[1] = (bhalf)v.y; b[2] = (bhalf)v.z; b[3] = (bhalf)v.w;
    *(bhalf4*)&tile[rl + 16 * p][c4] = b;
  }
  __syncthreads();
  int c = tid >> 2, r0 = (tid & 3) * 16;
  bhalf8 o0, o1;
#pragma unroll
  for (int j = 0; j < 8; ++j) { o0[j] = tile[r0 + j][c]; o1[j] = tile[r0 + 8 + j][c]; }
  *(bhalf8*)(out + (size_t)(bx + c) * R + by + r0) = o0;
  *(bhalf8*)(out + (size_t)(bx + c) * R + by + r0 + 8) = o1;
}

// -------- GEMM core: 128(M) x 64(N) tile, BK=64, DOUBLE-BUFFERED, 1 barrier/iter -----
// 4 waves stacked in M (wave tile 32x64, 2 m-frags). Prefetch of iter k+1 issued
// right after the barrier, so global_load_lds flies during iter-k MFMAs (attn
// kernel's proven pipeline). XOR-swizzled LDS. As = 2x8192 elems, Bs = 2x4096.
__device__ __forceinline__ void gemm_core_db(const bhalf* __restrict__ A,
                                             const bhalf* __restrict__ Bt,
                                             int Kstride, int Klen,
                                             int bm, int bn, int tid,
                                             bhalf* As, bhalf* Bs, f32x4 acc[2][4]) {
  int lane = tid & 63, wv = tid >> 6;
  int m16 = lane & 15, q4 = lane >> 4;
  int srow = tid >> 3;                       // 0..31
  int scol = ((tid & 7) ^ (srow & 7)) * 8;   // XOR-swizzled source col block
  const bhalf* asrc = A + (size_t)(bm + srow) * Kstride + scol;
  const bhalf* bsrc = Bt + (size_t)(bn + srow) * Kstride + scol;
  bhalf* adst = As + (wv * 8) * 64;
  bhalf* bdst = Bs + (wv * 8) * 64;
  int swz = m16 & 7;
  int nit = Klen >> 6;

  auto stage = [&](int it) {
    int buf = it & 1, k0 = it * 64;
#pragma unroll
    for (int c = 0; c < 4; ++c)
      __builtin_amdgcn_global_load_lds((gas_p)(asrc + (size_t)(c * 32) * Kstride + k0),
                                       (las_p)(adst + buf * 8192 + c * 2048), 16, 0, 0);
#pragma unroll
    for (int c = 0; c < 2; ++c)
      __builtin_amdgcn_global_load_lds((gas_p)(bsrc + (size_t)(c * 32) * Kstride + k0),
                                       (las_p)(bdst + buf * 4096 + c * 2048), 16, 0, 0);
  };

  stage(0);
  for (int it = 0; it < nit; ++it) {
    __syncthreads();                 // vmcnt(0) drain: buf `it` ready; old reads done
    if (it + 1 < nit) stage(it + 1); // flies during this iter's MFMAs
    const bhalf* Ab = As + (it & 1) * 8192;
    const bhalf* Bb = Bs + (it & 1) * 4096;
    bhalf8 af[2][2], bf[4][2];
#pragma unroll
    for (int mi = 0; mi < 2; ++mi)
#pragma unroll
      for (int ks = 0; ks < 2; ++ks)
        af[mi][ks] = *(const bhalf8*)&Ab[(wv * 32 + mi * 16 + m16) * 64 +
                                         (((ks * 4 + q4) ^ swz) * 8)];
#pragma unroll
    for (int ni = 0; ni < 4; ++ni)
#pragma unroll
      for (int ks = 0; ks < 2; ++ks)
        bf[ni][ks] = *(const bhalf8*)&Bb[(ni * 16 + m16) * 64 +
                                         (((ks * 4 + q4) ^ swz) * 8)];
#pragma unroll
    for (int mi = 0; mi < 2; ++mi)
#pragma unroll
      for (int ni = 0; ni < 4; ++ni) {
        acc[mi][ni] = __builtin_amdgcn_mfma_f32_16x16x32_bf16(af[mi][0], bf[ni][0], acc[mi][ni], 0, 0, 0);
        acc[mi][ni] = __builtin_amdgcn_mfma_f32_16x16x32_bf16(af[mi][1], bf[ni][1], acc[mi][ni], 0, 0, 0);
      }
  }
}

// ---------------- GEMM1 + fused RMSNorm + RoPE + split + cast (+ direct V^T) ---------
// 128x64 tile; N-tile == one head (h = blockIdx.x: 0..31 q, 32..39 k, 40..47 v).
__global__ __launch_bounds__(256) void gemm1_fused_k(const bhalf* __restrict__ A,
                                                     const bhalf* __restrict__ Bt,
                                                     const int* __restrict__ pos,
                                                     const float* __restrict__ qw,
                                                     const float* __restrict__ kw,
                                                     bhalf* __restrict__ qo,
                                                     bhalf* __restrict__ ko,
                                                     bhalf* __restrict__ vt) {
  __shared__ __align__(16) bhalf As[2 * 128 * 64];
  __shared__ __align__(16) bhalf Bs[2 * 64 * 64];
  int tid = threadIdx.x, lane = tid & 63, wv = tid >> 6;
  int m16 = lane & 15, q4 = lane >> 4;
  int bm = blockIdx.y * 128, bn = blockIdx.x * 64, h = blockIdx.x;
  f32x4 zero4 = {0.f, 0.f, 0.f, 0.f};
  f32x4 acc[2][4];
#pragma unroll
  for (int mi = 0; mi < 2; ++mi)
#pragma unroll
    for (int ni = 0; ni < 4; ++ni) acc[mi][ni] = zero4;

  gemm_core_db(A, Bt, HIDN, HIDN, bm, bn, tid, As, Bs, acc);

  if (h < 40) {
    float wd[4];
    const float* wptr = (h < 32) ? qw : kw;
#pragma unroll
    for (int ni = 0; ni < 4; ++ni) wd[ni] = wptr[ni * 16 + m16];
    float f0 = exp2f((float)m16 * -0.6228615177913804f);
    float f1 = f0 * 0.001f;  // theta^(-16/32) = 1e-3
#pragma unroll
    for (int mi = 0; mi < 2; ++mi)
#pragma unroll
      for (int r = 0; r < 4; ++r) {
        int trow = bm + wv * 32 + mi * 16 + q4 * 4 + r;
        float x0 = acc[mi][0][r], x1 = acc[mi][1][r], x2 = acc[mi][2][r], x3 = acc[mi][3][r];
        float ss = x0 * x0 + x1 * x1 + x2 * x2 + x3 * x3;
        ss += __shfl_xor(ss, 1);
        ss += __shfl_xor(ss, 2);
        ss += __shfl_xor(ss, 4);
        ss += __shfl_xor(ss, 8);
        float sc = rsqrtf(ss * (1.0f / 64.0f) + 1e-5f);
        float y0 = x0 * sc * wd[0], y1 = x1 * sc * wd[1];
        float y2 = x2 * sc * wd[2], y3 = x3 * sc * wd[3];
        float p = (float)pos[trow];
        float a0 = p * f0, a1 = p * f1;
        float c0 = cosf(a0), s0 = sinf(a0), c1 = cosf(a1), s1 = sinf(a1);
        float o0 = y0 * c0 - y2 * s0, o2 = y2 * c0 + y0 * s0;
        float o1 = y1 * c1 - y3 * s1, o3 = y3 * c1 + y1 * s1;
        bhalf* dst = (h < 32) ? (qo + (size_t)trow * 2048 + h * 64 + m16)
                              : (ko + (size_t)trow * 512 + (h - 32) * 64 + m16);
        dst[0] = (bhalf)o0; dst[16] = (bhalf)o1; dst[32] = (bhalf)o2; dst[48] = (bhalf)o3;
      }
  } else {
    // V: write transposed directly — vt[(h-40)*64 + d][trow]
#pragma unroll
    for (int mi = 0; mi < 2; ++mi)
#pragma unroll
      for (int r = 0; r < 4; ++r) {
        int trow = bm + wv * 32 + mi * 16 + q4 * 4 + r;
#pragma unroll
        for (int ni = 0; ni < 4; ++ni)
          vt[(size_t)((h - 40) * 64 + ni * 16 + m16) * 2048 + trow] = (bhalf)acc[mi][ni][r];
      }
  }
}

// ---------------- GEMM2 (128x64 tile, split-K=2): partial fp32 out ----------------
__global__ __launch_bounds__(256) void gemm2_k(const bhalf* __restrict__ A,
                                               const bhalf* __restrict__ Bt,
                                               float* __restrict__ Cpart) {
  __shared__ __align__(16) bhalf As[2 * 128 * 64];
  __shared__ __align__(16) bhalf Bs[2 * 64 * 64];
  int tid = threadIdx.x, lane = tid & 63, wv = tid >> 6;
  int m16 = lane & 15, q4 = lane >> 4;
  int bm = blockIdx.y * 128, bn = blockIdx.x * 64;
  int slice = blockIdx.z;
  f32x4 zero4 = {0.f, 0.f, 0.f, 0.f};
  f32x4 acc[2][4];
#pragma unroll
  for (int mi = 0; mi < 2; ++mi)
#pragma unroll
    for (int ni = 0; ni < 4; ++ni) acc[mi][ni] = zero4;

  gemm_core_db(A + slice * 1024, Bt + slice * 1024, HIDN, 1024, bm, bn, tid, As, Bs, acc);

  float* C = Cpart + (size_t)slice * (T_SEQ * HIDN);
#pragma unroll
  for (int mi = 0; mi < 2; ++mi)
#pragma unroll
    for (int r = 0; r < 4; ++r) {
      size_t base = (size_t)(bm + wv * 32 + mi * 16 + q4 * 4 + r) * 2048 + bn + m16;
      C[base] = acc[mi][0][r]; C[base + 16] = acc[mi][1][r];
      C[base + 32] = acc[mi][2][r]; C[base + 48] = acc[mi][3][r];
    }
}

// ---------------- split-K reduce: out = p0 + p1 ----------------
__global__ __launch_bounds__(256) void add2_k(const float* __restrict__ p0,
                                              const float* __restrict__ p1,
                                              float* __restrict__ out) {
  int i = (blockIdx.x * 256 + threadIdx.x) * 4;
  float4 a = *(const float4*)(p0 + i);
  float4 b = *(const float4*)(p1 + i);
  float4 o = {a.x + b.x, a.y + b.y, a.z + b.z, a.w + b.w};
  *(float4*)(out + i) = o;
}

// ---------------- flash attention (causal GQA), fixed-max softmax ----------------
// (R4 version — verified best.) grid (NQH, 32): block = (head, 64 q-rows),
// qt = 31 - by (heavy first). 4 waves; wave owns 16 q-rows. s-chunk 64, K/V^T
// double-buffered via global_load_lds + XOR swizzle, 1 barrier/chunk. Interior
// chunks take an unmasked fast path; only the diagonal chunk (c==qt) masks.
__global__ __launch_bounds__(256) void attn_k(const bhalf* __restrict__ q,
                                              const bhalf* __restrict__ k,
                                              const bhalf* __restrict__ vt,
                                              bhalf* __restrict__ o) {
  __shared__ __align__(16) bhalf Kb[2][4096];
  __shared__ __align__(16) bhalf Vb[2][4096];
  __shared__ __align__(16) bhalf Pb[4][16][72];
  int tid = threadIdx.x, lane = tid & 63, w = tid >> 6;
  int h = blockIdx.x, kh = h >> 2;
  int qt = 31 - blockIdx.y;
  int qb = qt * 64;
  int m16 = lane & 15, q4 = lane >> 4;
  int wrow0 = qb + w * 16;

  const float C1 = 0.18033688011112042f;  // 0.125 * log2(e)
  const float C2 = 11.541560327111707f;   // 8 * log2(e)

  const bhalf* qp = q + (size_t)(wrow0 + m16) * 2048 + h * 64;
  bhalf8 qf0 = *(const bhalf8*)(qp + q4 * 8);
  bhalf8 qf1 = *(const bhalf8*)(qp + 32 + q4 * 8);

  int srow = tid >> 3;
  int scol = ((tid & 7) ^ (srow & 7)) * 8;
  const bhalf* ksrc = k + (size_t)srow * 512 + kh * 64 + scol;
  const bhalf* vsrc = vt + (size_t)(kh * 64 + srow) * 2048 + scol;
  bhalf* kdst = &Kb[0][0] + w * 512;
  bhalf* vdst = &Vb[0][0] + w * 512;

  auto stage = [&](int c) {
    int buf = c & 1, s0 = c * 64;
#pragma unroll
    for (int j = 0; j < 2; ++j) {
      __builtin_amdgcn_global_load_lds((gas_p)(ksrc + (size_t)(s0 + j * 32) * 512),
                                       (las_p)(kdst + buf * 4096 + j * 2048), 16, 0, 0);
      __builtin_amdgcn_global_load_lds((gas_p)(vsrc + (size_t)(j * 32) * 2048 + s0),
                                       (las_p)(vdst + buf * 4096 + j * 2048), 16, 0, 0);
    }
  };

  f32x4 zero4 = {0.f, 0.f, 0.f, 0.f};
  f32x4 oac[4];
  float psum[4] = {0.f, 0.f, 0.f, 0.f};
#pragma unroll
  for (int ni = 0; ni < 4; ++ni) oac[ni] = zero4;
  int swz = m16 & 7;

  stage(0);
  for (int c = 0; c <= qt; ++c) {
    __syncthreads();
    if (c < qt) stage(c + 1);
    int buf = c & 1, s0 = c * 64;
    if (c < qt) {
      bhalf8 kf[4][2];
#pragma unroll
      for (int st = 0; st < 4; ++st)
#pragma unroll
        for (int ks = 0; ks < 2; ++ks)
          kf[st][ks] = *(const bhalf8*)&Kb[buf][(st * 16 + m16) * 64 + (((ks * 4 + q4) ^ swz) * 8)];
      f32x4 sv[4];
#pragma unroll
      for (int st = 0; st < 4; ++st) {
        f32x4 t0 = __builtin_amdgcn_mfma_f32_16x16x32_bf16(qf0, kf[st][0], zero4, 0, 0, 0);
        sv[st] = __builtin_amdgcn_mfma_f32_16x16x32_bf16(qf1, kf[st][1], t0, 0, 0, 0);
      }
#pragma unroll
      for (int st = 0; st < 4; ++st)
#pragma unroll
        for (int r = 0; r < 4; ++r) {
          float pe = exp2f(sv[st][r] * C1 - C2);
          psum[r] += pe;
          Pb[w][q4 * 4 + r][st * 16 + m16] = (bhalf)pe;
        }
      bhalf8 vf[4][2];
#pragma unroll
      for (int ni = 0; ni < 4; ++ni)
#pragma unroll
        for (int ks = 0; ks < 2; ++ks)
          vf[ni][ks] = *(const bhalf8*)&Vb[buf][(ni * 16 + m16) * 64 + (((ks * 4 + q4) ^ swz) * 8)];
      bhalf8 ap0 = *(const bhalf8*)&Pb[w][m16][q4 * 8];
      bhalf8 ap1 = *(const bhalf8*)&Pb[w][m16][32 + q4 * 8];
#pragma unroll
      for (int ni = 0; ni < 4; ++ni) {
        oac[ni] = __builtin_amdgcn_mfma_f32_16x16x32_bf16(ap0, vf[ni][0], oac[ni], 0, 0, 0);
        oac[ni] = __builtin_amdgcn_mfma_f32_16x16x32_bf16(ap1, vf[ni][1], oac[ni], 0, 0, 0);
      }
    } else {
      bhalf8 kf[4][2];
      f32x4 sv[4];
#pragma unroll
      for (int st = 0; st < 4; ++st)
        if (st <= w) {
#pragma unroll
          for (int ks = 0; ks < 2; ++ks)
            kf[st][ks] = *(const bhalf8*)&Kb[buf][(st * 16 + m16) * 64 + (((ks * 4 + q4) ^ swz) * 8)];
          f32x4 t0 = __builtin_amdgcn_mfma_f32_16x16x32_bf16(qf0, kf[st][0], zero4, 0, 0, 0);
          sv[st] = __builtin_amdgcn_mfma_f32_16x16x32_bf16(qf1, kf[st][1], t0, 0, 0, 0);
        }
      int stwr = (w >= 2) ? 3 : 1;
#pragma unroll
      for (int st = 0; st < 4; ++st) {
        if (st > stwr) continue;
#pragma unroll
        for (int r = 0; r < 4; ++r) {
          float pe = 0.f;
          if (st <= w) {
            int trow = wrow0 + q4 * 4 + r;
            int col = s0 + st * 16 + m16;
            pe = (col <= trow) ? exp2f(sv[st][r] * C1 - C2) : 0.f;
          }
          psum[r] += pe;
          Pb[w][q4 * 4 + r][st * 16 + m16] = (bhalf)pe;
        }
      }
      int ksmax = (w >= 2) ? 1 : 0;
      bhalf8 vf[4][2];
#pragma unroll
      for (int ni = 0; ni < 4; ++ni)
#pragma unroll
        for (int ks = 0; ks < 2; ++ks)
          if (ks <= ksmax)
            vf[ni][ks] = *(const bhalf8*)&Vb[buf][(ni * 16 + m16) * 64 + (((ks * 4 + q4) ^ swz) * 8)];
      bhalf8 ap0 = *(const bhalf8*)&Pb[w][m16][q4 * 8];
#pragma unroll
      for (int ni = 0; ni < 4; ++ni)
        oac[ni] = __builtin_amdgcn_mfma_f32_16x16x32_bf16(ap0, vf[ni][0], oac[ni], 0, 0, 0);
      if (ksmax) {
        bhalf8 ap1 = *(const bhalf8*)&Pb[w][m16][32 + q4 * 8];
#pragma unroll
        for (int ni = 0; ni < 4; ++ni)
          oac[ni] = __builtin_amdgcn_mfma_f32_16x16x32_bf16(ap1, vf[ni][1], oac[ni], 0, 0, 0);
      }
    }
  }
#pragma unroll
  for (int r = 0; r < 4; ++r) {
    float ps = psum[r];
    ps += __shfl_xor(ps, 1);
    ps += __shfl_xor(ps, 2);
    ps += __shfl_xor(ps, 4);
    ps += __shfl_xor(ps, 8);
    psum[r] = 1.0f / ps;
  }
#pragma unroll
  for (int ni = 0; ni < 4; ++ni)
#pragma unroll
    for (int r = 0; r < 4; ++r) {
      int trow = wrow0 + q4 * 4 + r;
      o[(size_t)trow * 2048 + h * 64 + ni * 16 + m16] = (bhalf)(oac[ni][r] * psum[r]);
    }
}

extern "C" void kernel_launch(void* const* d_in, const int* in_sizes, int n_in,
                              void* d_out, int out_size, void* d_ws, size_t ws_size,
                              hipStream_t stream) {
  const int* positions = (const int*)d_in[0];
  const float* hidden  = (const float*)d_in[1];
  const float* w_qkv   = (const float*)d_in[2];
  const float* w_out   = (const float*)d_in[3];
  const float* q_ln    = (const float*)d_in[4];
  const float* k_ln    = (const float*)d_in[5];
  float* out = (float*)d_out;

  char* wsp = (char*)d_ws;
  bhalf* woutT   = (bhalf*)(wsp);                 //  0 .. 8.39 MB
  bhalf* attn_bf = (bhalf*)(wsp + 8388608);       //  8.39 .. 16.78
  float* part0   = (float*)(wsp + 16777216);      // 16.78 .. 33.55 (overlays hid/wqkvT)
  float* part1   = (float*)(wsp + 33554432);      // 33.55 .. 50.33
  bhalf* hid_bf  = (bhalf*)(wsp + 16777216);      // dead after gemm1
  bhalf* wqkvT   = (bhalf*)(wsp + 25165824);      // dead after gemm1
  bhalf* q_bf    = (bhalf*)(wsp + 50331648);      // 50.33 .. 58.72
  bhalf* k_bf    = (bhalf*)(wsp + 58720256);      // 58.72 .. 60.82
  bhalf* vt_g    = (bhalf*)(wsp + 60817408);      // 60.82 .. 62.91

  cast_bf16_k<<<T_SEQ * HIDN / 1024, 256, 0, stream>>>(hidden, hid_bf, T_SEQ * HIDN);
  transpose_cast64_k<<<dim3(NQKV / 64, HIDN / 64), 256, 0, stream>>>(w_qkv, wqkvT, HIDN, NQKV);
  transpose_cast64_k<<<dim3(HIDN / 64, HIDN / 64), 256, 0, stream>>>(w_out, woutT, HIDN, HIDN);
  gemm1_fused_k<<<dim3(NQKV / 64, T_SEQ / 128), 256, 0, stream>>>(
      hid_bf, wqkvT, positions, q_ln, k_ln, q_bf, k_bf, vt_g);
  attn_k<<<dim3(NQH, 32), 256, 0, stream>>>(q_bf, k_bf, vt_g, attn_bf);
  gemm2_k<<<dim3(HIDN / 64, T_SEQ / 128, 2), 256, 0, stream>>>(attn_bf, woutT, part0);
  add2_k<<<T_SEQ * HIDN / 1024, 256, 0, stream>>>(part0, part1, out);
}